// Round 7
// baseline (27.644 us; speedup 1.0000x reference)
//
#include <hip/hip_runtime.h>

// BinaryPositionEmbedding: out[t, :] = sum over set bits i of x[t] of w[i, :]
// x: (4, 8192) int32 -> 32768 tokens; w: (13, 1024) f32; out: (4,8192,1024) f32
//
// Ladder: nt-stores 34.8 -> normal stores 28.1 -> TOK32 27.4 us.
// Falsified: occupancy (28 waves/CU slower than 16), table decomposition
// (L2 reads compete with stores, +3.4 us), nt stores (-9%).
// R7 lever: bit->float via uniform ternary (s_cselect 0x3f800000/0 +
// v_fmac_f32 v,s,v) instead of v_cvt_f32_i32, cutting per-token VALU between
// consecutive 1KB wave stores from 65 to 52 ops.

#define NBITS 13
#define DMOD 1024
#define TOK_PER_BLOCK 32

typedef float f32x4 __attribute__((ext_vector_type(4)));

__global__ __launch_bounds__(256, 4) void bpe_direct(
    const int* __restrict__ x, const float* __restrict__ w,
    float* __restrict__ out, int n_tokens) {
    const int d0 = threadIdx.x * 4;

    // This thread's slice of the weight table, kept in registers (13 x f32x4).
    f32x4 wr[NBITS];
#pragma unroll
    for (int i = 0; i < NBITS; ++i)
        wr[i] = *reinterpret_cast<const f32x4*>(&w[i * DMOD + d0]);

    const int tok0 = blockIdx.x * TOK_PER_BLOCK;
    float* dst = &out[(size_t)tok0 * DMOD + d0];

    if ((tok0 + TOK_PER_BLOCK) <= n_tokens) {
#pragma unroll
        for (int k = 0; k < TOK_PER_BLOCK; ++k) {
            const int pos = x[tok0 + k];            // uniform -> s_load
            f32x4 s = {0.f, 0.f, 0.f, 0.f};
#pragma unroll
            for (int i = 0; i < NBITS; ++i) {
                // uniform bit -> scalar cselect of float const, feeds v_fmac
                const float b = ((pos >> i) & 1) ? 1.0f : 0.0f;
                s.x = fmaf(b, wr[i].x, s.x);
                s.y = fmaf(b, wr[i].y, s.y);
                s.z = fmaf(b, wr[i].z, s.z);
                s.w = fmaf(b, wr[i].w, s.w);
            }
            *reinterpret_cast<f32x4*>(dst + (size_t)k * DMOD) = s;
        }
    } else {
        for (int k = 0; k < TOK_PER_BLOCK; ++k) {
            const int tok = tok0 + k;
            if (tok >= n_tokens) break;
            const int pos = x[tok];
            f32x4 s = {0.f, 0.f, 0.f, 0.f};
#pragma unroll
            for (int i = 0; i < NBITS; ++i) {
                const float b = ((pos >> i) & 1) ? 1.0f : 0.0f;
                s.x = fmaf(b, wr[i].x, s.x);
                s.y = fmaf(b, wr[i].y, s.y);
                s.z = fmaf(b, wr[i].z, s.z);
                s.w = fmaf(b, wr[i].w, s.w);
            }
            *reinterpret_cast<f32x4*>(dst + (size_t)k * DMOD) = s;
        }
    }
}

extern "C" void kernel_launch(void* const* d_in, const int* in_sizes, int n_in,
                              void* d_out, int out_size, void* d_ws, size_t ws_size,
                              hipStream_t stream) {
    const int* x = (const int*)d_in[0];     // 32768 int32 positions
    const float* w = (const float*)d_in[1]; // 13 x 1024 f32
    float* out = (float*)d_out;             // 32768 x 1024 f32

    const int n_tokens = in_sizes[0];
    const int blocks = (n_tokens + TOK_PER_BLOCK - 1) / TOK_PER_BLOCK;
    bpe_direct<<<blocks, 256, 0, stream>>>(x, w, out, n_tokens);
}